// Round 18
// baseline (267.533 us; speedup 1.0000x reference)
//
#include <hip/hip_runtime.h>
#include <math.h>

#define NG 6
#define KD 40
#define CB 1024
#define NB 32
#define TP 2000
#define RPB 256              // rows per block (4 waves x 64: 2 sets of 32)
#define THREADS 256
#define NBLK 250             // 64000 / 256
#define ZN 480000
#define ZG 80000
#define BAND_D 6e-3f         // |approx_dist - np_dist| bound with >=2x margin
#define PK_G 98304           // shorts per group (32 tiles * 3072, hi+lo)
#define PK_T 3072            // shorts per tile
#define CHS 6144             // shorts per chunk (2 tiles)
#define NCH 16               // chunks

typedef __attribute__((ext_vector_type(8))) short bf16x8;
typedef __attribute__((ext_vector_type(16))) float f32x16;

__device__ __forceinline__ unsigned short bf16rne(float v) {
  unsigned u = __float_as_uint(v);
  return (unsigned short)((u + 0x7FFFu + ((u >> 16) & 1u)) >> 16);
}
__device__ __forceinline__ float bf16val(unsigned short h) {
  return __uint_as_float(((unsigned)h) << 16);
}
__device__ __forceinline__ void bf16split(float v, unsigned short& h, unsigned short& l) {
  h = bf16rne(v);
  l = bf16rne(v - bf16val(h));
}
__device__ __forceinline__ bf16x8 ldfrag16(const unsigned short* p) {
  union { uint4 q; bf16x8 v; } u;
  u.q = *(const uint4*)p;
  return u.v;
}
__device__ __forceinline__ void gload_lds16(const void* g, void* l) {
  __builtin_amdgcn_global_load_lds(
      (const __attribute__((address_space(1))) unsigned int*)g,
      (__attribute__((address_space(3))) unsigned int*)l, 16, 0, 0);
}

// ---- prep: et[g][c][k] fp32; np-exact ||e||^2; fragment-ordered bf16 hi/lo pack (r11)
__global__ void prep_kernel(const float* __restrict__ emb, float* __restrict__ et,
                            float* __restrict__ e2, unsigned short* __restrict__ epack) {
  int c = blockIdx.x * blockDim.x + threadIdx.x;
  int g = blockIdx.y;
  if (c >= CB) return;
  const float* eg = emb + (size_t)g * KD * CB;
  float ev[KD];
  float* o = et + ((size_t)g * CB + c) * KD;
  float s = 0.f;
#pragma unroll
  for (int k = 0; k < KD; ++k) {
    float v = eg[k * CB + c];
    ev[k] = v;
    o[k] = v;
    s = __fadd_rn(s, __fmul_rn(v, v));   // np-exact serial unfused
  }
  e2[g * CB + c] = s;

  float sv = 0.5f * s;                    // 3-way bf16 split of the seed
  unsigned short p0 = bf16rne(sv);
  float v1 = sv - bf16val(p0);
  unsigned short p1 = bf16rne(v1);
  unsigned short p2 = bf16rne(v1 - bf16val(p1));

  int tile = c >> 5, j32 = c & 31;
  unsigned short* tb = epack + (size_t)g * PK_G + (size_t)tile * PK_T;
#pragma unroll
  for (int s2 = 0; s2 < 3; ++s2)
#pragma unroll
    for (int gg = 0; gg < 2; ++gg) {
      union { uint4 q; unsigned short sh[8]; } uh, ul;
#pragma unroll
      for (int j = 0; j < 8; ++j) {
        int k = s2 * 16 + gg * 8 + j;
        if (k < KD) {
          bf16split(ev[k], uh.sh[j], ul.sh[j]);
        } else {
          uh.sh[j] = (k == 40) ? p0 : (k == 41) ? p1 : (k == 42) ? p2 : (unsigned short)0;
          ul.sh[j] = 0;
        }
      }
      unsigned short* ph = tb + ((size_t)(s2 * 2 + gg) * 32 + j32) * 8;
      *(uint4*)ph = uh.q;
      *(uint4*)(ph + 1536) = ul.q;
    }
}

__device__ __forceinline__ float npd_calc(const float* __restrict__ x,
                                          const float* __restrict__ ef,
                                          float e2c, float x2np) {
  float dot = 0.f;
#pragma unroll
  for (int k = 0; k < KD; ++k) dot = __fadd_rn(dot, __fmul_rn(x[k], ef[k]));
  return __fadd_rn(__fsub_rn(x2np, __fadd_rn(dot, dot)), e2c);
}

#define INS3(V, C) { \
    bool u1 = (V) < rd1, u2 = (V) < rd2, u3 = (V) < rd3; \
    rd3 = u2 ? rd2 : (u3 ? (V) : rd3); ri3 = u2 ? ri2 : (u3 ? (C) : ri3); \
    rd2 = u1 ? rd1 : (u2 ? (V) : rd2); ri2 = u1 ? ri1 : (u2 ? (C) : ri2); \
    rd1 = u1 ? (V) : rd1;              ri1 = u1 ? (C) : ri1; }

__global__ __launch_bounds__(THREADS, 3) void vq_kernel(
    const float* __restrict__ z, const float* __restrict__ et,
    const float* __restrict__ e2, const unsigned short* __restrict__ epack,
    float* __restrict__ out, float* __restrict__ partials) {
  const int g = blockIdx.y;
  const int bb = blockIdx.x;
  const int tid = threadIdx.x;
  const int lane = tid & 63;
  const int gg = lane >> 5;
  const int j32 = lane & 31;
  const int wid = tid >> 6;
  const int rid0 = bb * RPB + wid * 64 + j32;   // set A row
  const int rid1 = rid0 + 32;                   // set B row
  const int n0 = rid0 / TP, tt0 = rid0 - n0 * TP;
  const int n1 = rid1 / TP, tt1 = rid1 - n1 * TP;

  const float* etg = et + (size_t)g * CB * KD;
  const float* e2g = e2 + g * CB;
  const unsigned short* egrp = epack + (size_t)g * PK_G;

  __shared__ __align__(16) unsigned short sbuf[2][CHS];
  __shared__ float r0s[THREADS], r1s[THREADS];

#define STAGE(B, CH) { \
    const unsigned short* gsrc = egrp + (size_t)(CH) * CHS + wid * 512 + lane * 8; \
    unsigned short* lb = &sbuf[B][wid * 512]; \
    gload_lds16(gsrc, lb); \
    gload_lds16(gsrc + 2048, lb + 2048); \
    gload_lds16(gsrc + 4096, lb + 4096); }
  STAGE(0, 0)

  const float* zp0 = z + (size_t)n0 * ZN + (size_t)g * ZG + tt0;
  const float* zp1 = z + (size_t)n1 * ZN + (size_t)g * ZG + tt1;

  // ---- B fragments from -x for both row-sets (no persistent x[40]; x is
  // reloaded in the end phase). Static per-gg k-slices (verified r9-r16).
  bf16x8 xhA[3], xlA[3], xhB[3], xlB[3];
#define PACKF(DH, DL, ZP, B0) { \
    union { unsigned short s[8]; bf16x8 v; } uh, ul; \
    _Pragma("unroll") \
    for (int j = 0; j < 8; ++j) { \
      unsigned short h, l; bf16split(-(ZP)[(size_t)((B0) + j) * TP], h, l); \
      uh.s[j] = h; ul.s[j] = l; } \
    DH = uh.v; DL = ul.v; }
  if (gg == 0) {
    PACKF(xhA[0], xlA[0], zp0, 0)
    PACKF(xhA[1], xlA[1], zp0, 16)
    PACKF(xhA[2], xlA[2], zp0, 32)
    PACKF(xhB[0], xlB[0], zp1, 0)
    PACKF(xhB[1], xlB[1], zp1, 16)
    PACKF(xhB[2], xlB[2], zp1, 32)
  } else {
    PACKF(xhA[0], xlA[0], zp0, 8)
    PACKF(xhA[1], xlA[1], zp0, 24)
    PACKF(xhB[0], xlB[0], zp1, 8)
    PACKF(xhB[1], xlB[1], zp1, 24)
    union { unsigned short s[8]; bf16x8 v; } uo, uz;
#pragma unroll
    for (int j = 0; j < 8; ++j) {
      uo.s[j] = (j < 3) ? (unsigned short)0x3F80 : (unsigned short)0;
      uz.s[j] = 0;
    }
    xhA[2] = uo.v; xlA[2] = uz.v;
    xhB[2] = uo.v; xlB[2] = uz.v;
  }
#undef PACKF

  f32x16 zacc;
#pragma unroll
  for (int i = 0; i < 16; ++i) zacc[i] = 0.f;

  float d1A = INFINITY, d2xA = INFINITY;
  float d1B = INFINITY, d2xB = INFINITY;
  int g1A = 0, g1B = 0;

#define TRACKG(AV, TILE, D1V, D2XV, G1V) { \
    int cb = (TILE) * 32 + 4 * gg; \
    float q0 = fminf(fminf(fminf(AV[0], AV[1]), AV[2]), AV[3]); \
    float q1 = fminf(fminf(fminf(AV[4], AV[5]), AV[6]), AV[7]); \
    float q2 = fminf(fminf(fminf(AV[8], AV[9]), AV[10]), AV[11]); \
    float q3 = fminf(fminf(fminf(AV[12], AV[13]), AV[14]), AV[15]); \
    D2XV = fminf(D2XV, fmaxf(D1V, q0)); G1V = (q0 < D1V) ? (cb + 0) : G1V; D1V = fminf(D1V, q0); \
    D2XV = fminf(D2XV, fmaxf(D1V, q1)); G1V = (q1 < D1V) ? (cb + 8) : G1V; D1V = fminf(D1V, q1); \
    D2XV = fminf(D2XV, fmaxf(D1V, q2)); G1V = (q2 < D1V) ? (cb + 16) : G1V; D1V = fminf(D1V, q2); \
    D2XV = fminf(D2XV, fmaxf(D1V, q3)); G1V = (q3 < D1V) ? (cb + 24) : G1V; D1V = fminf(D1V, q3); }

// one tile: 6 frag reads shared by two interleaved 9-chains (sets A,B)
#define TILE2(TB, AA, AB) { \
    bf16x8 eh0 = ldfrag16(TB); \
    bf16x8 eh1 = ldfrag16((TB) + 512); \
    bf16x8 eh2 = ldfrag16((TB) + 1024); \
    bf16x8 el0 = ldfrag16((TB) + 1536); \
    bf16x8 el1 = ldfrag16((TB) + 2048); \
    bf16x8 el2 = ldfrag16((TB) + 2560); \
    AA = __builtin_amdgcn_mfma_f32_32x32x16_bf16(eh0, xhA[0], zacc, 0, 0, 0); \
    AB = __builtin_amdgcn_mfma_f32_32x32x16_bf16(eh0, xhB[0], zacc, 0, 0, 0); \
    AA = __builtin_amdgcn_mfma_f32_32x32x16_bf16(eh0, xlA[0], AA, 0, 0, 0); \
    AB = __builtin_amdgcn_mfma_f32_32x32x16_bf16(eh0, xlB[0], AB, 0, 0, 0); \
    AA = __builtin_amdgcn_mfma_f32_32x32x16_bf16(el0, xhA[0], AA, 0, 0, 0); \
    AB = __builtin_amdgcn_mfma_f32_32x32x16_bf16(el0, xhB[0], AB, 0, 0, 0); \
    AA = __builtin_amdgcn_mfma_f32_32x32x16_bf16(eh1, xhA[1], AA, 0, 0, 0); \
    AB = __builtin_amdgcn_mfma_f32_32x32x16_bf16(eh1, xhB[1], AB, 0, 0, 0); \
    AA = __builtin_amdgcn_mfma_f32_32x32x16_bf16(eh1, xlA[1], AA, 0, 0, 0); \
    AB = __builtin_amdgcn_mfma_f32_32x32x16_bf16(eh1, xlB[1], AB, 0, 0, 0); \
    AA = __builtin_amdgcn_mfma_f32_32x32x16_bf16(el1, xhA[1], AA, 0, 0, 0); \
    AB = __builtin_amdgcn_mfma_f32_32x32x16_bf16(el1, xhB[1], AB, 0, 0, 0); \
    AA = __builtin_amdgcn_mfma_f32_32x32x16_bf16(eh2, xhA[2], AA, 0, 0, 0); \
    AB = __builtin_amdgcn_mfma_f32_32x32x16_bf16(eh2, xhB[2], AB, 0, 0, 0); \
    AA = __builtin_amdgcn_mfma_f32_32x32x16_bf16(eh2, xlA[2], AA, 0, 0, 0); \
    AB = __builtin_amdgcn_mfma_f32_32x32x16_bf16(eh2, xlB[2], AB, 0, 0, 0); \
    AA = __builtin_amdgcn_mfma_f32_32x32x16_bf16(el2, xhA[2], AA, 0, 0, 0); \
    AB = __builtin_amdgcn_mfma_f32_32x32x16_bf16(el2, xhB[2], AB, 0, 0, 0); }

// single-tile 9-chain for one set (rare fallback only)
#define MFMA9(TB, AOUT, XH, XL) { \
    bf16x8 eh0 = ldfrag16(TB); \
    bf16x8 eh1 = ldfrag16((TB) + 512); \
    bf16x8 eh2 = ldfrag16((TB) + 1024); \
    bf16x8 el0 = ldfrag16((TB) + 1536); \
    bf16x8 el1 = ldfrag16((TB) + 2048); \
    bf16x8 el2 = ldfrag16((TB) + 2560); \
    AOUT = __builtin_amdgcn_mfma_f32_32x32x16_bf16(eh0, XH[0], zacc, 0, 0, 0); \
    AOUT = __builtin_amdgcn_mfma_f32_32x32x16_bf16(eh0, XL[0], AOUT, 0, 0, 0); \
    AOUT = __builtin_amdgcn_mfma_f32_32x32x16_bf16(el0, XH[0], AOUT, 0, 0, 0); \
    AOUT = __builtin_amdgcn_mfma_f32_32x32x16_bf16(eh1, XH[1], AOUT, 0, 0, 0); \
    AOUT = __builtin_amdgcn_mfma_f32_32x32x16_bf16(eh1, XL[1], AOUT, 0, 0, 0); \
    AOUT = __builtin_amdgcn_mfma_f32_32x32x16_bf16(el1, XH[1], AOUT, 0, 0, 0); \
    AOUT = __builtin_amdgcn_mfma_f32_32x32x16_bf16(eh2, XH[2], AOUT, 0, 0, 0); \
    AOUT = __builtin_amdgcn_mfma_f32_32x32x16_bf16(eh2, XL[2], AOUT, 0, 0, 0); \
    AOUT = __builtin_amdgcn_mfma_f32_32x32x16_bf16(el2, XH[2], AOUT, 0, 0, 0); }

  int cur = 0;
#pragma unroll 1
  for (int ch = 0; ch < NCH; ++ch) {
    if (ch + 1 < NCH) {
      STAGE(cur ^ 1, ch + 1)
      asm volatile("s_waitcnt vmcnt(3)" ::: "memory");  // chunk ch done; next 3 in flight
    } else {
      asm volatile("s_waitcnt vmcnt(0)" ::: "memory");
    }
    __builtin_amdgcn_s_barrier();
    {
      const unsigned short* tb0 = &sbuf[cur][lane * 8];
      f32x16 aA, aB;
      TILE2(tb0, aA, aB)
      TRACKG(aA, ch * 2, d1A, d2xA, g1A)
      TRACKG(aB, ch * 2, d1B, d2xB, g1B)
      const unsigned short* tb1 = &sbuf[cur][PK_T + lane * 8];
      TILE2(tb1, aA, aB)
      TRACKG(aA, ch * 2 + 1, d1A, d2xA, g1A)
      TRACKG(aB, ch * 2 + 1, d1B, d2xB, g1B)
    }
    __builtin_amdgcn_s_barrier();   // all waves done reading before next overwrite
    cur ^= 1;
  }

  const int n_lo = (bb * RPB) / TP;
  float lsA = 0.f, lsB = 0.f;

  // ---- end phase per set: reload x, np-exact group rescore, band flag,
  //      rare wave-level fallback (r13/r14-verified logic), epilogue.
#define ENDSET(NS, D2XV, G1V, XH, XL, ZPS) { \
    float x[KD]; \
    _Pragma("unroll") \
    for (int k = 0; k < KD; ++k) x[k] = (ZPS)[(size_t)k * TP]; \
    float x2np; \
    { float r[8]; \
      _Pragma("unroll") \
      for (int j = 0; j < 8; ++j) r[j] = __fmul_rn(x[j], x[j]); \
      _Pragma("unroll") \
      for (int i = 8; i < KD; i += 8) \
        _Pragma("unroll") \
        for (int j = 0; j < 8; ++j) \
          r[j] = __fadd_rn(r[j], __fmul_rn(x[i + j], x[i + j])); \
      x2np = __fadd_rn(__fadd_rn(__fadd_rn(r[0], r[1]), __fadd_rn(r[2], r[3])), \
                       __fadd_rn(__fadd_rn(r[4], r[5]), __fadd_rn(r[6], r[7]))); } \
    float bd = INFINITY; int bi = CB; \
    _Pragma("unroll") \
    for (int j = 0; j < 4; ++j) { \
      int c = (G1V) + j; \
      float d = npd_calc(x, etg + (size_t)c * KD, e2g[c], x2np); \
      if (d < bd) { bd = d; bi = c; } } \
    float dd2x = fmaf(2.f, (D2XV), x2np); \
    { float od = __shfl_xor(bd, 32); int oi = __shfl_xor(bi, 32); \
      float ox = __shfl_xor(dd2x, 32); \
      if (od < bd || (od == bd && oi < bi)) { bd = od; bi = oi; } \
      dd2x = fminf(dd2x, ox); } \
    bool flag = dd2x < bd + BAND_D; \
    if (__any(flag)) { \
      float rd1 = INFINITY, rd2 = INFINITY, rd3 = INFINITY; \
      int ri1 = 0, ri2 = 0, ri3 = 0; \
      _Pragma("unroll 1") \
      for (int tile = 0; tile < 32; ++tile) { \
        const unsigned short* tb = egrp + (size_t)tile * PK_T + lane * 8; \
        f32x16 a; \
        MFMA9(tb, a, XH, XL) \
        float gm0 = fminf(fminf(a[0], a[1]), fminf(a[2], a[3])); \
        float gm1 = fminf(fminf(a[4], a[5]), fminf(a[6], a[7])); \
        float gm2 = fminf(fminf(a[8], a[9]), fminf(a[10], a[11])); \
        float gm3 = fminf(fminf(a[12], a[13]), fminf(a[14], a[15])); \
        float tmin = fminf(fminf(gm0, gm1), fminf(gm2, gm3)); \
        if (tmin < rd3) { \
          int cb = tile * 32 + 4 * gg; \
          if (gm0 < rd3) { INS3(a[0], cb + 0) INS3(a[1], cb + 1) INS3(a[2], cb + 2) INS3(a[3], cb + 3) } \
          if (gm1 < rd3) { INS3(a[4], cb + 8) INS3(a[5], cb + 9) INS3(a[6], cb + 10) INS3(a[7], cb + 11) } \
          if (gm2 < rd3) { INS3(a[8], cb + 16) INS3(a[9], cb + 17) INS3(a[10], cb + 18) INS3(a[11], cb + 19) } \
          if (gm3 < rd3) { INS3(a[12], cb + 24) INS3(a[13], cb + 25) INS3(a[14], cb + 26) INS3(a[15], cb + 27) } \
        } \
      } \
      float dd1 = fmaf(2.f, rd1, x2np); \
      float dd2 = fmaf(2.f, rd2, x2np); \
      float dd3 = fmaf(2.f, rd3, x2np); \
      bd = dd1; bi = ri1; \
      bool exact = false; \
      { bool need2 = dd2 < dd1 + BAND_D; \
        bool need3 = dd3 < dd1 + BAND_D; \
        if (need2 || need3) { \
          int cA = ri1; \
          int cB = need2 ? ri2 : 0x7fffffff; \
          int cC = need3 ? ri3 : 0x7fffffff; \
          int t; \
          if (cA > cB) { t = cA; cA = cB; cB = t; } \
          if (cB > cC) { t = cB; cB = cC; cC = t; } \
          if (cA > cB) { t = cA; cA = cB; cB = t; } \
          bd = INFINITY; bi = CB; \
          if (cA < CB) { float d = npd_calc(x, etg + (size_t)cA * KD, e2g[cA], x2np); if (d < bd) { bd = d; bi = cA; } } \
          if (cB < CB) { float d = npd_calc(x, etg + (size_t)cB * KD, e2g[cB], x2np); if (d < bd) { bd = d; bi = cB; } } \
          if (cC < CB) { float d = npd_calc(x, etg + (size_t)cC * KD, e2g[cC], x2np); if (d < bd) { bd = d; bi = cC; } } \
          exact = true; } } \
      { float od = __shfl_xor(bd, 32); \
        bool race = fabsf(bd - od) < BAND_D; \
        if (race && !exact) bd = npd_calc(x, etg + (size_t)bi * KD, e2g[bi], x2np); \
        float od2 = __shfl_xor(bd, 32); \
        int oi = __shfl_xor(bi, 32); \
        if (od2 < bd || (od2 == bd && oi < bi)) { bd = od2; bi = oi; } } \
    } \
    const float4* eb4 = (const float4*)(etg + (size_t)bi * KD); \
    float* op = out + ((ZPS) - z); \
    float ls = 0.f; \
    if (gg == 0) { \
      _Pragma("unroll") \
      for (int p = 0; p < 5; ++p) { \
        float4 v = eb4[p]; \
        int k = 4 * p; \
        float e0 = __fsub_rn(v.x, x[k + 0]); ls = fmaf(e0, e0, ls); op[(size_t)(k + 0) * TP] = __fadd_rn(x[k + 0], e0); \
        float e1 = __fsub_rn(v.y, x[k + 1]); ls = fmaf(e1, e1, ls); op[(size_t)(k + 1) * TP] = __fadd_rn(x[k + 1], e1); \
        float e2v = __fsub_rn(v.z, x[k + 2]); ls = fmaf(e2v, e2v, ls); op[(size_t)(k + 2) * TP] = __fadd_rn(x[k + 2], e2v); \
        float e3 = __fsub_rn(v.w, x[k + 3]); ls = fmaf(e3, e3, ls); op[(size_t)(k + 3) * TP] = __fadd_rn(x[k + 3], e3); \
      } \
    } else { \
      _Pragma("unroll") \
      for (int p = 5; p < 10; ++p) { \
        float4 v = eb4[p]; \
        int k = 4 * p; \
        float e0 = __fsub_rn(v.x, x[k + 0]); ls = fmaf(e0, e0, ls); op[(size_t)(k + 0) * TP] = __fadd_rn(x[k + 0], e0); \
        float e1 = __fsub_rn(v.y, x[k + 1]); ls = fmaf(e1, e1, ls); op[(size_t)(k + 1) * TP] = __fadd_rn(x[k + 1], e1); \
        float e2v = __fsub_rn(v.z, x[k + 2]); ls = fmaf(e2v, e2v, ls); op[(size_t)(k + 2) * TP] = __fadd_rn(x[k + 2], e2v); \
        float e3 = __fsub_rn(v.w, x[k + 3]); ls = fmaf(e3, e3, ls); op[(size_t)(k + 3) * TP] = __fadd_rn(x[k + 3], e3); \
      } \
    } \
    if ((NS) == n_lo) lsA += ls; else lsB += ls; \
  }

  ENDSET(n0, d2xA, g1A, xhA, xlA, zp0)
  ENDSET(n1, d2xB, g1B, xhB, xlB, zp1)

  // ---- deterministic segmented block reduce (block straddles <=1 n boundary)
  r0s[tid] = lsA;
  r1s[tid] = lsB;
  __syncthreads();
  for (int s = THREADS / 2; s > 0; s >>= 1) {
    if (tid < s) {
      r0s[tid] += r0s[tid + s];
      r1s[tid] += r1s[tid + s];
    }
    __syncthreads();
  }
  if (tid == 0) {
    partials[((size_t)g * NBLK + bb) * 2 + 0] = r0s[0];
    partials[((size_t)g * NBLK + bb) * 2 + 1] = r1s[0];
  }
}

// ---- final: fixed-order reduction of per-block partials -> vq_loss[n]
__global__ void loss_kernel(const float* __restrict__ partials,
                            float* __restrict__ vq) {
  int n = threadIdx.x;
  if (n >= NB) return;
  float acc = 0.f;
  for (int g = 0; g < NG; ++g) {
    float s = 0.f;
    int b0 = (n * TP) / RPB;
    int b1 = ((n + 1) * TP - 1) / RPB;
    for (int b = b0; b <= b1; ++b) {
      int n_lo = (b * RPB) / TP;
      s += partials[((size_t)g * NBLK + b) * 2 + ((n == n_lo) ? 0 : 1)];
    }
    acc += 0.25f * (s / 80000.0f);
  }
  vq[n] = acc / 6.0f;
}

extern "C" void kernel_launch(void* const* d_in, const int* in_sizes, int n_in,
                              void* d_out, int out_size, void* d_ws, size_t ws_size,
                              hipStream_t stream) {
  const float* z = (const float*)d_in[0];
  const float* emb = (const float*)d_in[1];
  float* out = (float*)d_out;

  float* et = (float*)d_ws;                          // 983,040 B
  float* e2 = et + (size_t)NG * CB * KD;             // 24,576 B
  float* partials = e2 + (size_t)NG * CB;            // 24,000 B
  unsigned short* epack = (unsigned short*)((char*)d_ws + 1031680);  // 1,179,648 B

  prep_kernel<<<dim3(CB / 256, NG), 256, 0, stream>>>(emb, et, e2, epack);
  vq_kernel<<<dim3(NBLK, NG), THREADS, 0, stream>>>(z, et, e2, epack, out, partials);
  loss_kernel<<<1, 64, 0, stream>>>(partials, out + (size_t)NB * 60 * 8000);
}

// Round 19
// 260.224 us; speedup vs baseline: 1.0281x; 1.0281x over previous
//
#include <hip/hip_runtime.h>
#include <math.h>

#define NG 6
#define KD 40
#define CB 1024
#define NB 32
#define TP 2000
#define RPB 128              // rows per block (4 waves x 32, gg-paired)
#define THREADS 256
#define NBLK 500             // 64000 / 128
#define ZN 480000
#define ZG 80000
#define BAND_D 6e-2f         // hard bound on |approx_dist - np_dist| for fp16 scan
#define PKH_G 49152          // shorts per group (32 tiles * 1536, fp16 single)
#define PKH_T 1536           // shorts per tile
#define CHS 6144             // shorts per chunk (4 tiles)
#define NCH 8                // chunks

typedef __attribute__((ext_vector_type(8))) _Float16 f16x8;
typedef __attribute__((ext_vector_type(16))) float f32x16;

__device__ __forceinline__ unsigned short f16h(float v) {
  union { _Float16 h; unsigned short s; } u;
  u.h = (_Float16)v;   // v_cvt_f16_f32 RNE
  return u.s;
}
__device__ __forceinline__ float f16f(unsigned short s) {
  union { _Float16 h; unsigned short s; } u;
  u.s = s;
  return (float)u.h;
}
__device__ __forceinline__ f16x8 ldfragh(const unsigned short* p) {
  union { uint4 q; f16x8 v; } u;
  u.q = *(const uint4*)p;
  return u.v;
}
__device__ __forceinline__ void gload_lds16(const void* g, void* l) {
  __builtin_amdgcn_global_load_lds(
      (const __attribute__((address_space(1))) unsigned int*)g,
      (__attribute__((address_space(3))) unsigned int*)l, 16, 0, 0);
}

// ---- prep: et[g][c][k] fp32; np-exact ||e||^2; fragment-ordered fp16 pack
__global__ void prep_kernel(const float* __restrict__ emb, float* __restrict__ et,
                            float* __restrict__ e2, unsigned short* __restrict__ epackh) {
  int c = blockIdx.x * blockDim.x + threadIdx.x;
  int g = blockIdx.y;
  if (c >= CB) return;
  const float* eg = emb + (size_t)g * KD * CB;
  float ev[KD];
  float* o = et + ((size_t)g * CB + c) * KD;
  float s = 0.f;
#pragma unroll
  for (int k = 0; k < KD; ++k) {
    float v = eg[k * CB + c];
    ev[k] = v;
    o[k] = v;
    s = __fadd_rn(s, __fmul_rn(v, v));   // np-exact serial unfused
  }
  e2[g * CB + c] = s;

  float sv = 0.5f * s;                    // fp16 2-term split of the seed
  unsigned short p0 = f16h(sv);
  unsigned short p1 = f16h(sv - f16f(p0));

  int tile = c >> 5, j32 = c & 31;
  unsigned short* tb = epackh + (size_t)g * PKH_G + (size_t)tile * PKH_T;
#pragma unroll
  for (int s2 = 0; s2 < 3; ++s2)
#pragma unroll
    for (int gg = 0; gg < 2; ++gg) {
      union { uint4 q; unsigned short sh[8]; } uh;
#pragma unroll
      for (int j = 0; j < 8; ++j) {
        int k = s2 * 16 + gg * 8 + j;
        if (k < KD) uh.sh[j] = f16h(ev[k]);
        else uh.sh[j] = (k == 40) ? p0 : (k == 41) ? p1 : (unsigned short)0;
      }
      *(uint4*)(tb + ((size_t)(s2 * 2 + gg) * 32 + j32) * 8) = uh.q;
    }
}

__device__ __forceinline__ float npd_calc(const float* __restrict__ x,
                                          const float* __restrict__ ef,
                                          float e2c, float x2np) {
  float dot = 0.f;
#pragma unroll
  for (int k = 0; k < KD; ++k) dot = __fadd_rn(dot, __fmul_rn(x[k], ef[k]));
  return __fadd_rn(__fsub_rn(x2np, __fadd_rn(dot, dot)), e2c);
}

__global__ __launch_bounds__(THREADS, 3) void vq_kernel(
    const float* __restrict__ z, const float* __restrict__ et,
    const float* __restrict__ e2, const unsigned short* __restrict__ epackh,
    float* __restrict__ out, float* __restrict__ partials) {
  const int g = blockIdx.y;
  const int bb = blockIdx.x;
  const int tid = threadIdx.x;
  const int lane = tid & 63;
  const int gg = lane >> 5;
  const int j32 = lane & 31;
  const int wid = tid >> 6;
  const int rowloc = wid * 32 + j32;
  const int rid = bb * RPB + rowloc;
  const int n = rid / TP;
  const int tt = rid - n * TP;

  const float* etg = et + (size_t)g * CB * KD;
  const float* e2g = e2 + g * CB;
  const unsigned short* egrp = epackh + (size_t)g * PKH_G;

  __shared__ __align__(16) unsigned short sbuf[2][CHS];
  __shared__ float r0s[THREADS], r1s[THREADS];

#define STAGE(B, CH) { \
    const unsigned short* gsrc = egrp + (size_t)(CH) * CHS + wid * 512 + lane * 8; \
    unsigned short* lb = &sbuf[B][wid * 512]; \
    gload_lds16(gsrc, lb); \
    gload_lds16(gsrc + 2048, lb + 2048); \
    gload_lds16(gsrc + 4096, lb + 4096); }
  STAGE(0, 0)

  // ---- row x in registers; x2np (numpy pairwise-8, verified r6)
  const float* zp = z + (size_t)n * ZN + (size_t)g * ZG + tt;
  float x[KD];
#pragma unroll
  for (int k = 0; k < KD; ++k) x[k] = zp[(size_t)k * TP];
  float x2np;
  {
    float r[8];
#pragma unroll
    for (int j = 0; j < 8; ++j) r[j] = __fmul_rn(x[j], x[j]);
#pragma unroll
    for (int i = 8; i < KD; i += 8)
#pragma unroll
      for (int j = 0; j < 8; ++j)
        r[j] = __fadd_rn(r[j], __fmul_rn(x[i + j], x[i + j]));
    x2np = __fadd_rn(__fadd_rn(__fadd_rn(r[0], r[1]), __fadd_rn(r[2], r[3])),
                     __fadd_rn(__fadd_rn(r[4], r[5]), __fadd_rn(r[6], r[7])));
  }

  // ---- B fragments: -x as fp16 2-term (xh + xl), static per-gg k-slices
  f16x8 xh[3], xl[3];
#define PACKF(DH, DL, B0) { \
    union { unsigned short s[8]; f16x8 v; } uh, ul; \
    _Pragma("unroll") \
    for (int j = 0; j < 8; ++j) { \
      float y = -x[(B0) + j]; \
      unsigned short h = f16h(y); \
      uh.s[j] = h; ul.s[j] = f16h(y - f16f(h)); } \
    DH = uh.v; DL = ul.v; }
  if (gg == 0) {
    PACKF(xh[0], xl[0], 0)
    PACKF(xh[1], xl[1], 16)
    PACKF(xh[2], xl[2], 32)
  } else {
    PACKF(xh[0], xl[0], 8)
    PACKF(xh[1], xl[1], 24)
    union { unsigned short s[8]; f16x8 v; } uo, uz;
#pragma unroll
    for (int j = 0; j < 8; ++j) {
      uo.s[j] = (j < 2) ? (unsigned short)0x3C00 : (unsigned short)0;  // 1.0h at seed slots
      uz.s[j] = 0;
    }
    xh[2] = uo.v;
    xl[2] = uz.v;
  }
#undef PACKF

  f32x16 zacc;
#pragma unroll
  for (int i = 0; i < 16; ++i) zacc[i] = 0.f;

  // ---- branchless tracking (verified r14): d1 + group base + d2x
  float d1 = INFINITY, d2x = INFINITY;
  int grp1 = 0;

#define TRACKG(AV, TILE) { \
    int cb = (TILE) * 32 + 4 * gg; \
    float q0 = fminf(fminf(fminf(AV[0], AV[1]), AV[2]), AV[3]); \
    float q1 = fminf(fminf(fminf(AV[4], AV[5]), AV[6]), AV[7]); \
    float q2 = fminf(fminf(fminf(AV[8], AV[9]), AV[10]), AV[11]); \
    float q3 = fminf(fminf(fminf(AV[12], AV[13]), AV[14]), AV[15]); \
    d2x = fminf(d2x, fmaxf(d1, q0)); grp1 = (q0 < d1) ? (cb + 0) : grp1; d1 = fminf(d1, q0); \
    d2x = fminf(d2x, fmaxf(d1, q1)); grp1 = (q1 < d1) ? (cb + 8) : grp1; d1 = fminf(d1, q1); \
    d2x = fminf(d2x, fmaxf(d1, q2)); grp1 = (q2 < d1) ? (cb + 16) : grp1; d1 = fminf(d1, q2); \
    d2x = fminf(d2x, fmaxf(d1, q3)); grp1 = (q3 < d1) ? (cb + 24) : grp1; d1 = fminf(d1, q3); }

// one tile: 3 ds_read (E fp16 single) feeding a 6-MFMA chain (e.xh + e.xl)
#define MFMA6(TB, AOUT) { \
    f16x8 e0 = ldfragh(TB); \
    f16x8 e1 = ldfragh((TB) + 512); \
    f16x8 e2f = ldfragh((TB) + 1024); \
    AOUT = __builtin_amdgcn_mfma_f32_32x32x16_f16(e0, xh[0], zacc, 0, 0, 0); \
    AOUT = __builtin_amdgcn_mfma_f32_32x32x16_f16(e0, xl[0], AOUT, 0, 0, 0); \
    AOUT = __builtin_amdgcn_mfma_f32_32x32x16_f16(e1, xh[1], AOUT, 0, 0, 0); \
    AOUT = __builtin_amdgcn_mfma_f32_32x32x16_f16(e1, xl[1], AOUT, 0, 0, 0); \
    AOUT = __builtin_amdgcn_mfma_f32_32x32x16_f16(e2f, xh[2], AOUT, 0, 0, 0); \
    AOUT = __builtin_amdgcn_mfma_f32_32x32x16_f16(e2f, xl[2], AOUT, 0, 0, 0); }

  int cur = 0;
#pragma unroll 1
  for (int ch = 0; ch < NCH; ++ch) {
    if (ch + 1 < NCH) {
      STAGE(cur ^ 1, ch + 1)
      asm volatile("s_waitcnt vmcnt(3)" ::: "memory");  // chunk ch done; next 3 in flight
    } else {
      asm volatile("s_waitcnt vmcnt(0)" ::: "memory");
    }
    __builtin_amdgcn_s_barrier();
    {
      f32x16 a0, a1, a2, a3;
      MFMA6(&sbuf[cur][0 * PKH_T + lane * 8], a0)
      MFMA6(&sbuf[cur][1 * PKH_T + lane * 8], a1)
      MFMA6(&sbuf[cur][2 * PKH_T + lane * 8], a2)
      MFMA6(&sbuf[cur][3 * PKH_T + lane * 8], a3)
      TRACKG(a0, ch * 4 + 0)
      TRACKG(a1, ch * 4 + 1)
      TRACKG(a2, ch * 4 + 2)
      TRACKG(a3, ch * 4 + 3)
    }
    __builtin_amdgcn_s_barrier();   // all waves done reading before next overwrite
    cur ^= 1;
  }

  // ---- end phase: np-exact rescore of the winning GROUP's 4 codes (r14-verified)
  float bd = INFINITY;
  int bi = CB;
#pragma unroll
  for (int j = 0; j < 4; ++j) {
    int c = grp1 + j;
    float d = npd_calc(x, etg + (size_t)c * KD, e2g[c], x2np);
    if (d < bd) { bd = d; bi = c; }
  }
  float dd2x = fmaf(2.f, d2x, x2np);

  // cross-half merge ((d,c) order; both bd are np-exact)
  {
    float od = __shfl_xor(bd, 32);
    int oi = __shfl_xor(bi, 32);
    float odd2x = __shfl_xor(dd2x, 32);
    if (od < bd || (od == bd && oi < bi)) { bd = od; bi = oi; }
    dd2x = fminf(dd2x, odd2x);
  }
  bool flag = dd2x < bd + BAND_D;  // another group might np-beat the winner

  // ---- rare wave-level fallback: exact top-3 rescan from GLOBAL epackh (r13/r14)
  if (__any(flag)) {
    float rd1 = INFINITY, rd2 = INFINITY, rd3 = INFINITY;
    int ri1 = 0, ri2 = 0, ri3 = 0;
#define INS3(V, C) { \
      bool u1 = (V) < rd1, u2 = (V) < rd2, u3 = (V) < rd3; \
      rd3 = u2 ? rd2 : (u3 ? (V) : rd3); ri3 = u2 ? ri2 : (u3 ? (C) : ri3); \
      rd2 = u1 ? rd1 : (u2 ? (V) : rd2); ri2 = u1 ? ri1 : (u2 ? (C) : ri2); \
      rd1 = u1 ? (V) : rd1;              ri1 = u1 ? (C) : ri1; }
#pragma unroll 1
    for (int tile = 0; tile < 32; ++tile) {
      const unsigned short* tb = egrp + (size_t)tile * PKH_T + lane * 8;
      f32x16 a;
      MFMA6(tb, a)
      {
        float gm0 = fminf(fminf(a[0], a[1]), fminf(a[2], a[3]));
        float gm1 = fminf(fminf(a[4], a[5]), fminf(a[6], a[7]));
        float gm2 = fminf(fminf(a[8], a[9]), fminf(a[10], a[11]));
        float gm3 = fminf(fminf(a[12], a[13]), fminf(a[14], a[15]));
        float tmin = fminf(fminf(gm0, gm1), fminf(gm2, gm3));
        if (tmin < rd3) {
          int cb = tile * 32 + 4 * gg;
          if (gm0 < rd3) { INS3(a[0], cb + 0) INS3(a[1], cb + 1) INS3(a[2], cb + 2) INS3(a[3], cb + 3) }
          if (gm1 < rd3) { INS3(a[4], cb + 8) INS3(a[5], cb + 9) INS3(a[6], cb + 10) INS3(a[7], cb + 11) }
          if (gm2 < rd3) { INS3(a[8], cb + 16) INS3(a[9], cb + 17) INS3(a[10], cb + 18) INS3(a[11], cb + 19) }
          if (gm3 < rd3) { INS3(a[12], cb + 24) INS3(a[13], cb + 25) INS3(a[14], cb + 26) INS3(a[15], cb + 27) }
        }
      }
    }
    float dd1 = fmaf(2.f, rd1, x2np);
    float dd2 = fmaf(2.f, rd2, x2np);
    float dd3 = fmaf(2.f, rd3, x2np);
    bd = dd1; bi = ri1;
    bool exact = false;
    {
      bool need2 = dd2 < dd1 + BAND_D;
      bool need3 = dd3 < dd1 + BAND_D;
      if (need2 || need3) {
        int cA = ri1;
        int cB = need2 ? ri2 : 0x7fffffff;
        int cC = need3 ? ri3 : 0x7fffffff;
        int t;
        if (cA > cB) { t = cA; cA = cB; cB = t; }
        if (cB > cC) { t = cB; cB = cC; cC = t; }
        if (cA > cB) { t = cA; cA = cB; cB = t; }
        bd = INFINITY; bi = CB;
        if (cA < CB) { float d = npd_calc(x, etg + (size_t)cA * KD, e2g[cA], x2np); if (d < bd) { bd = d; bi = cA; } }
        if (cB < CB) { float d = npd_calc(x, etg + (size_t)cB * KD, e2g[cB], x2np); if (d < bd) { bd = d; bi = cB; } }
        if (cC < CB) { float d = npd_calc(x, etg + (size_t)cC * KD, e2g[cC], x2np); if (d < bd) { bd = d; bi = cC; } }
        exact = true;
      }
    }
    {
      float od = __shfl_xor(bd, 32);
      bool race = fabsf(bd - od) < BAND_D;
      if (race && !exact) bd = npd_calc(x, etg + (size_t)bi * KD, e2g[bi], x2np);
      float od2 = __shfl_xor(bd, 32);
      int oi = __shfl_xor(bi, 32);
      if (od2 < bd || (od2 == bd && oi < bi)) { bd = od2; bi = oi; }
    }
  }

  // ---- epilogue: STE write + loss partial, static k-halves per gg
  const float4* eb4 = (const float4*)(etg + (size_t)bi * KD);
  float* op = out + (size_t)n * ZN + (size_t)g * ZG + tt;
  float ls = 0.f;
  if (gg == 0) {
#pragma unroll
    for (int p = 0; p < 5; ++p) {
      float4 v = eb4[p];
      int k = 4 * p;
      float e0 = __fsub_rn(v.x, x[k + 0]); ls = fmaf(e0, e0, ls); op[(size_t)(k + 0) * TP] = __fadd_rn(x[k + 0], e0);
      float e1 = __fsub_rn(v.y, x[k + 1]); ls = fmaf(e1, e1, ls); op[(size_t)(k + 1) * TP] = __fadd_rn(x[k + 1], e1);
      float e2v = __fsub_rn(v.z, x[k + 2]); ls = fmaf(e2v, e2v, ls); op[(size_t)(k + 2) * TP] = __fadd_rn(x[k + 2], e2v);
      float e3 = __fsub_rn(v.w, x[k + 3]); ls = fmaf(e3, e3, ls); op[(size_t)(k + 3) * TP] = __fadd_rn(x[k + 3], e3);
    }
  } else {
#pragma unroll
    for (int p = 5; p < 10; ++p) {
      float4 v = eb4[p];
      int k = 4 * p;
      float e0 = __fsub_rn(v.x, x[k + 0]); ls = fmaf(e0, e0, ls); op[(size_t)(k + 0) * TP] = __fadd_rn(x[k + 0], e0);
      float e1 = __fsub_rn(v.y, x[k + 1]); ls = fmaf(e1, e1, ls); op[(size_t)(k + 1) * TP] = __fadd_rn(x[k + 1], e1);
      float e2v = __fsub_rn(v.z, x[k + 2]); ls = fmaf(e2v, e2v, ls); op[(size_t)(k + 2) * TP] = __fadd_rn(x[k + 2], e2v);
      float e3 = __fsub_rn(v.w, x[k + 3]); ls = fmaf(e3, e3, ls); op[(size_t)(k + 3) * TP] = __fadd_rn(x[k + 3], e3);
    }
  }

  // ---- deterministic segmented block reduce (block straddles <=1 n boundary)
  const int n_lo = (bb * RPB) / TP;
  r0s[tid] = (n == n_lo) ? ls : 0.f;
  r1s[tid] = (n == n_lo) ? 0.f : ls;
  __syncthreads();
  for (int s = THREADS / 2; s > 0; s >>= 1) {
    if (tid < s) {
      r0s[tid] += r0s[tid + s];
      r1s[tid] += r1s[tid + s];
    }
    __syncthreads();
  }
  if (tid == 0) {
    partials[((size_t)g * NBLK + bb) * 2 + 0] = r0s[0];
    partials[((size_t)g * NBLK + bb) * 2 + 1] = r1s[0];
  }
}

// ---- final: fixed-order reduction of per-block partials -> vq_loss[n]
__global__ void loss_kernel(const float* __restrict__ partials,
                            float* __restrict__ vq) {
  int n = threadIdx.x;
  if (n >= NB) return;
  float acc = 0.f;
  for (int g = 0; g < NG; ++g) {
    float s = 0.f;
    int b0 = (n * TP) / RPB;
    int b1 = ((n + 1) * TP - 1) / RPB;
    for (int b = b0; b <= b1; ++b) {
      int n_lo = (b * RPB) / TP;
      s += partials[((size_t)g * NBLK + b) * 2 + ((n == n_lo) ? 0 : 1)];
    }
    acc += 0.25f * (s / 80000.0f);
  }
  vq[n] = acc / 6.0f;
}

extern "C" void kernel_launch(void* const* d_in, const int* in_sizes, int n_in,
                              void* d_out, int out_size, void* d_ws, size_t ws_size,
                              hipStream_t stream) {
  const float* z = (const float*)d_in[0];
  const float* emb = (const float*)d_in[1];
  float* out = (float*)d_out;

  float* et = (float*)d_ws;                          // 983,040 B
  float* e2 = et + (size_t)NG * CB * KD;             // 24,576 B
  float* partials = e2 + (size_t)NG * CB;            // 24,000 B
  unsigned short* epackh = (unsigned short*)((char*)d_ws + 1031680);  // 589,824 B

  prep_kernel<<<dim3(CB / 256, NG), 256, 0, stream>>>(emb, et, e2, epackh);
  vq_kernel<<<dim3(NBLK, NG), THREADS, 0, stream>>>(z, et, e2, epackh, out, partials);
  loss_kernel<<<1, 64, 0, stream>>>(partials, out + (size_t)NB * 60 * 8000);
}

// Round 20
// 228.688 us; speedup vs baseline: 1.1699x; 1.1379x over previous
//
#include <hip/hip_runtime.h>
#include <math.h>

#define NG 6
#define KD 40
#define CB 1024
#define NB 32
#define TP 2000
#define RPB 128              // rows per block (4 waves x 32, gg-paired)
#define THREADS 256
#define NBLK 500             // 64000 / 128
#define ZN 480000
#define ZG 80000
#define BAND_D 6e-3f         // |approx_dist - np_dist| bound with >=2x margin
#define PK_G 98304           // shorts per group (32 tiles * 3072, hi+lo)
#define PK_T 3072            // shorts per tile
#define CHS 6144             // shorts per chunk (2 tiles)
#define NCH 16               // chunks

typedef __attribute__((ext_vector_type(8))) short bf16x8;
typedef __attribute__((ext_vector_type(16))) float f32x16;

__device__ __forceinline__ unsigned short bf16rne(float v) {
  unsigned u = __float_as_uint(v);
  return (unsigned short)((u + 0x7FFFu + ((u >> 16) & 1u)) >> 16);
}
__device__ __forceinline__ float bf16val(unsigned short h) {
  return __uint_as_float(((unsigned)h) << 16);
}
__device__ __forceinline__ void bf16split(float v, unsigned short& h, unsigned short& l) {
  h = bf16rne(v);
  l = bf16rne(v - bf16val(h));
}
__device__ __forceinline__ bf16x8 ldfrag16(const unsigned short* p) {
  union { uint4 q; bf16x8 v; } u;
  u.q = *(const uint4*)p;
  return u.v;
}
__device__ __forceinline__ void gload_lds16(const void* g, void* l) {
  __builtin_amdgcn_global_load_lds(
      (const __attribute__((address_space(1))) unsigned int*)g,
      (__attribute__((address_space(3))) unsigned int*)l, 16, 0, 0);
}

// ---- prep: et[g][c][k] fp32; np-exact ||e||^2; fragment-ordered bf16 hi/lo pack (r11)
__global__ void prep_kernel(const float* __restrict__ emb, float* __restrict__ et,
                            float* __restrict__ e2, unsigned short* __restrict__ epack) {
  int c = blockIdx.x * blockDim.x + threadIdx.x;
  int g = blockIdx.y;
  if (c >= CB) return;
  const float* eg = emb + (size_t)g * KD * CB;
  float ev[KD];
  float* o = et + ((size_t)g * CB + c) * KD;
  float s = 0.f;
#pragma unroll
  for (int k = 0; k < KD; ++k) {
    float v = eg[k * CB + c];
    ev[k] = v;
    o[k] = v;
    s = __fadd_rn(s, __fmul_rn(v, v));   // np-exact serial unfused
  }
  e2[g * CB + c] = s;

  float sv = 0.5f * s;                    // 3-way bf16 split of the seed
  unsigned short p0 = bf16rne(sv);
  float v1 = sv - bf16val(p0);
  unsigned short p1 = bf16rne(v1);
  unsigned short p2 = bf16rne(v1 - bf16val(p1));

  int tile = c >> 5, j32 = c & 31;
  unsigned short* tb = epack + (size_t)g * PK_G + (size_t)tile * PK_T;
#pragma unroll
  for (int s2 = 0; s2 < 3; ++s2)
#pragma unroll
    for (int gg = 0; gg < 2; ++gg) {
      union { uint4 q; unsigned short sh[8]; } uh, ul;
#pragma unroll
      for (int j = 0; j < 8; ++j) {
        int k = s2 * 16 + gg * 8 + j;
        if (k < KD) {
          bf16split(ev[k], uh.sh[j], ul.sh[j]);
        } else {
          uh.sh[j] = (k == 40) ? p0 : (k == 41) ? p1 : (k == 42) ? p2 : (unsigned short)0;
          ul.sh[j] = 0;
        }
      }
      unsigned short* ph = tb + ((size_t)(s2 * 2 + gg) * 32 + j32) * 8;
      *(uint4*)ph = uh.q;
      *(uint4*)(ph + 1536) = ul.q;
    }
}

__device__ __forceinline__ float npd_calc(const float* __restrict__ x,
                                          const float* __restrict__ ef,
                                          float e2c, float x2np) {
  float dot = 0.f;
#pragma unroll
  for (int k = 0; k < KD; ++k) dot = __fadd_rn(dot, __fmul_rn(x[k], ef[k]));
  return __fadd_rn(__fsub_rn(x2np, __fadd_rn(dot, dot)), e2c);
}

__global__ __launch_bounds__(THREADS, 3) void vq_kernel(
    const float* __restrict__ z, const float* __restrict__ et,
    const float* __restrict__ e2, const unsigned short* __restrict__ epack,
    float* __restrict__ out, float* __restrict__ partials) {
  const int g = blockIdx.y;
  const int bb = blockIdx.x;
  const int tid = threadIdx.x;
  const int lane = tid & 63;
  const int gg = lane >> 5;
  const int j32 = lane & 31;
  const int wid = tid >> 6;
  const int rowloc = wid * 32 + j32;
  const int rid = bb * RPB + rowloc;
  const int n = rid / TP;
  const int tt = rid - n * TP;

  const float* etg = et + (size_t)g * CB * KD;
  const float* e2g = e2 + g * CB;
  const unsigned short* egrp = epack + (size_t)g * PK_G;

  __shared__ __align__(16) unsigned short sbuf[2][CHS];
  __shared__ float r0s[THREADS], r1s[THREADS];

#define STAGE(B, CH) { \
    const unsigned short* gsrc = egrp + (size_t)(CH) * CHS + wid * 512 + lane * 8; \
    unsigned short* lb = &sbuf[B][wid * 512]; \
    gload_lds16(gsrc, lb); \
    gload_lds16(gsrc + 2048, lb + 2048); \
    gload_lds16(gsrc + 4096, lb + 4096); }
  STAGE(0, 0)

  // ---- row x in registers; x2np (numpy pairwise-8, verified r6)
  const float* zp = z + (size_t)n * ZN + (size_t)g * ZG + tt;
  float x[KD];
#pragma unroll
  for (int k = 0; k < KD; ++k) x[k] = zp[(size_t)k * TP];
  float x2np;
  {
    float r[8];
#pragma unroll
    for (int j = 0; j < 8; ++j) r[j] = __fmul_rn(x[j], x[j]);
#pragma unroll
    for (int i = 8; i < KD; i += 8)
#pragma unroll
      for (int j = 0; j < 8; ++j)
        r[j] = __fadd_rn(r[j], __fmul_rn(x[i + j], x[i + j]));
    x2np = __fadd_rn(__fadd_rn(__fadd_rn(r[0], r[1]), __fadd_rn(r[2], r[3])),
                     __fadd_rn(__fadd_rn(r[4], r[5]), __fadd_rn(r[6], r[7])));
  }

  // ---- B fragments from -x, static per-gg k-slices (verified r9-r16)
  bf16x8 xh[3], xl[3];
#define PACK8(DH, DL, B0) { \
    union { unsigned short s[8]; bf16x8 v; } uh, ul; \
    _Pragma("unroll") \
    for (int j = 0; j < 8; ++j) { \
      unsigned short h, l; bf16split(-x[(B0) + j], h, l); \
      uh.s[j] = h; ul.s[j] = l; } \
    DH = uh.v; DL = ul.v; }
  if (gg == 0) {
    PACK8(xh[0], xl[0], 0)
    PACK8(xh[1], xl[1], 16)
    PACK8(xh[2], xl[2], 32)
  } else {
    PACK8(xh[0], xl[0], 8)
    PACK8(xh[1], xl[1], 24)
    union { unsigned short s[8]; bf16x8 v; } uh;
#pragma unroll
    for (int j = 0; j < 8; ++j) uh.s[j] = (j < 3) ? (unsigned short)0x3F80 : (unsigned short)0;
    xh[2] = uh.v;
    union { unsigned short s[8]; bf16x8 v; } uz;
#pragma unroll
    for (int j = 0; j < 8; ++j) uz.s[j] = 0;
    xl[2] = uz.v;
  }
#undef PACK8

  f32x16 zacc;
#pragma unroll
  for (int i = 0; i < 16; ++i) zacc[i] = 0.f;

  // ---- branchless tracking, deepened: (d1,grp1) best group w/ id,
  //      (d2x,grp2) second-best group w/ id, d3x third-best min (no id).
  float d1 = INFINITY, d2x = INFINITY, d3x = INFINITY;
  int grp1 = 0, grp2 = 0;

#define TRACKG(AV, TILE) { \
    int cb = (TILE) * 32 + 4 * gg; \
    float q0 = fminf(fminf(fminf(AV[0], AV[1]), AV[2]), AV[3]); \
    float q1 = fminf(fminf(fminf(AV[4], AV[5]), AV[6]), AV[7]); \
    float q2 = fminf(fminf(fminf(AV[8], AV[9]), AV[10]), AV[11]); \
    float q3 = fminf(fminf(fminf(AV[12], AV[13]), AV[14]), AV[15]); \
    { bool b1 = q0 < d1, b2 = q0 < d2x; \
      d3x = fminf(d3x, fmaxf(d2x, q0)); \
      grp2 = b1 ? grp1 : (b2 ? (cb + 0) : grp2); \
      d2x = fminf(d2x, fmaxf(d1, q0)); \
      grp1 = b1 ? (cb + 0) : grp1; d1 = fminf(d1, q0); } \
    { bool b1 = q1 < d1, b2 = q1 < d2x; \
      d3x = fminf(d3x, fmaxf(d2x, q1)); \
      grp2 = b1 ? grp1 : (b2 ? (cb + 8) : grp2); \
      d2x = fminf(d2x, fmaxf(d1, q1)); \
      grp1 = b1 ? (cb + 8) : grp1; d1 = fminf(d1, q1); } \
    { bool b1 = q2 < d1, b2 = q2 < d2x; \
      d3x = fminf(d3x, fmaxf(d2x, q2)); \
      grp2 = b1 ? grp1 : (b2 ? (cb + 16) : grp2); \
      d2x = fminf(d2x, fmaxf(d1, q2)); \
      grp1 = b1 ? (cb + 16) : grp1; d1 = fminf(d1, q2); } \
    { bool b1 = q3 < d1, b2 = q3 < d2x; \
      d3x = fminf(d3x, fmaxf(d2x, q3)); \
      grp2 = b1 ? grp1 : (b2 ? (cb + 24) : grp2); \
      d2x = fminf(d2x, fmaxf(d1, q3)); \
      grp1 = b1 ? (cb + 24) : grp1; d1 = fminf(d1, q3); } }

// single-tile 9-chain (used in main loop and fallback)
#define MFMA9(TB, AOUT) { \
    bf16x8 eh0 = ldfrag16(TB); \
    bf16x8 eh1 = ldfrag16((TB) + 512); \
    bf16x8 eh2 = ldfrag16((TB) + 1024); \
    bf16x8 el0 = ldfrag16((TB) + 1536); \
    bf16x8 el1 = ldfrag16((TB) + 2048); \
    bf16x8 el2 = ldfrag16((TB) + 2560); \
    AOUT = __builtin_amdgcn_mfma_f32_32x32x16_bf16(eh0, xh[0], zacc, 0, 0, 0); \
    AOUT = __builtin_amdgcn_mfma_f32_32x32x16_bf16(eh0, xl[0], AOUT, 0, 0, 0); \
    AOUT = __builtin_amdgcn_mfma_f32_32x32x16_bf16(el0, xh[0], AOUT, 0, 0, 0); \
    AOUT = __builtin_amdgcn_mfma_f32_32x32x16_bf16(eh1, xh[1], AOUT, 0, 0, 0); \
    AOUT = __builtin_amdgcn_mfma_f32_32x32x16_bf16(eh1, xl[1], AOUT, 0, 0, 0); \
    AOUT = __builtin_amdgcn_mfma_f32_32x32x16_bf16(el1, xh[1], AOUT, 0, 0, 0); \
    AOUT = __builtin_amdgcn_mfma_f32_32x32x16_bf16(eh2, xh[2], AOUT, 0, 0, 0); \
    AOUT = __builtin_amdgcn_mfma_f32_32x32x16_bf16(eh2, xl[2], AOUT, 0, 0, 0); \
    AOUT = __builtin_amdgcn_mfma_f32_32x32x16_bf16(el2, xh[2], AOUT, 0, 0, 0); }

  int cur = 0;
#pragma unroll 1
  for (int ch = 0; ch < NCH; ++ch) {
    if (ch + 1 < NCH) {
      STAGE(cur ^ 1, ch + 1)
      asm volatile("s_waitcnt vmcnt(3)" ::: "memory");  // chunk ch done; next 3 in flight
    } else {
      asm volatile("s_waitcnt vmcnt(0)" ::: "memory");
    }
    __builtin_amdgcn_s_barrier();
    {
      f32x16 a0, a1;
      MFMA9(&sbuf[cur][lane * 8], a0)
      MFMA9(&sbuf[cur][PK_T + lane * 8], a1)
      TRACKG(a0, ch * 2)
      TRACKG(a1, ch * 2 + 1)
    }
    __builtin_amdgcn_s_barrier();   // all waves done reading before next overwrite
    cur ^= 1;
  }

  // ---- end phase: np-exact rescore of BOTH top-2 groups' codes (8 codes),
  //      (d,c)-ordered updates = order-independent np first-min.
  float bd = INFINITY;
  int bi = CB;
#define UPD(DV, CV) { if ((DV) < bd || ((DV) == bd && (CV) < bi)) { bd = (DV); bi = (CV); } }
#pragma unroll
  for (int j = 0; j < 4; ++j) {
    int c = grp1 + j;
    float d = npd_calc(x, etg + (size_t)c * KD, e2g[c], x2np);
    UPD(d, c)
  }
#pragma unroll
  for (int j = 0; j < 4; ++j) {
    int c = grp2 + j;
    float d = npd_calc(x, etg + (size_t)c * KD, e2g[c], x2np);
    UPD(d, c)
  }
  float dd3x = fmaf(2.f, d3x, x2np);

  // cross-half merge ((d,c) order; both bd are np-exact over 8 codes each)
  {
    float od = __shfl_xor(bd, 32);
    int oi = __shfl_xor(bi, 32);
    float odd3x = __shfl_xor(dd3x, 32);
    if (od < bd || (od == bd && oi < bi)) { bd = od; bi = oi; }
    dd3x = fminf(dd3x, odd3x);
  }
  bool flag = dd3x < bd + BAND_D;  // a third group might np-beat the winner (rare^2)

  // ---- rare wave-level fallback: exact top-3 rescan from GLOBAL epack (r13/r14)
  if (__any(flag)) {
    float rd1 = INFINITY, rd2 = INFINITY, rd3 = INFINITY;
    int ri1 = 0, ri2 = 0, ri3 = 0;
#define INS3(V, C) { \
      bool u1 = (V) < rd1, u2 = (V) < rd2, u3 = (V) < rd3; \
      rd3 = u2 ? rd2 : (u3 ? (V) : rd3); ri3 = u2 ? ri2 : (u3 ? (C) : ri3); \
      rd2 = u1 ? rd1 : (u2 ? (V) : rd2); ri2 = u1 ? ri1 : (u2 ? (C) : ri2); \
      rd1 = u1 ? (V) : rd1;              ri1 = u1 ? (C) : ri1; }
#pragma unroll 1
    for (int tile = 0; tile < 32; ++tile) {
      const unsigned short* tb = egrp + (size_t)tile * PK_T + lane * 8;
      f32x16 a;
      MFMA9(tb, a)
      {
        float gm0 = fminf(fminf(a[0], a[1]), fminf(a[2], a[3]));
        float gm1 = fminf(fminf(a[4], a[5]), fminf(a[6], a[7]));
        float gm2 = fminf(fminf(a[8], a[9]), fminf(a[10], a[11]));
        float gm3 = fminf(fminf(a[12], a[13]), fminf(a[14], a[15]));
        float tmin = fminf(fminf(gm0, gm1), fminf(gm2, gm3));
        if (tmin < rd3) {
          int cb = tile * 32 + 4 * gg;
          if (gm0 < rd3) { INS3(a[0], cb + 0) INS3(a[1], cb + 1) INS3(a[2], cb + 2) INS3(a[3], cb + 3) }
          if (gm1 < rd3) { INS3(a[4], cb + 8) INS3(a[5], cb + 9) INS3(a[6], cb + 10) INS3(a[7], cb + 11) }
          if (gm2 < rd3) { INS3(a[8], cb + 16) INS3(a[9], cb + 17) INS3(a[10], cb + 18) INS3(a[11], cb + 19) }
          if (gm3 < rd3) { INS3(a[12], cb + 24) INS3(a[13], cb + 25) INS3(a[14], cb + 26) INS3(a[15], cb + 27) }
        }
      }
    }
    float dd1 = fmaf(2.f, rd1, x2np);
    float dd2 = fmaf(2.f, rd2, x2np);
    float dd3 = fmaf(2.f, rd3, x2np);
    bd = dd1; bi = ri1;
    bool exact = false;
    {
      bool need2 = dd2 < dd1 + BAND_D;
      bool need3 = dd3 < dd1 + BAND_D;
      if (need2 || need3) {
        int cA = ri1;
        int cB = need2 ? ri2 : 0x7fffffff;
        int cC = need3 ? ri3 : 0x7fffffff;
        int t;
        if (cA > cB) { t = cA; cA = cB; cB = t; }
        if (cB > cC) { t = cB; cB = cC; cC = t; }
        if (cA > cB) { t = cA; cA = cB; cB = t; }
        bd = INFINITY; bi = CB;
        if (cA < CB) { float d = npd_calc(x, etg + (size_t)cA * KD, e2g[cA], x2np); if (d < bd) { bd = d; bi = cA; } }
        if (cB < CB) { float d = npd_calc(x, etg + (size_t)cB * KD, e2g[cB], x2np); if (d < bd) { bd = d; bi = cB; } }
        if (cC < CB) { float d = npd_calc(x, etg + (size_t)cC * KD, e2g[cC], x2np); if (d < bd) { bd = d; bi = cC; } }
        exact = true;
      }
    }
    {
      float od = __shfl_xor(bd, 32);
      bool race = fabsf(bd - od) < BAND_D;
      if (race && !exact) bd = npd_calc(x, etg + (size_t)bi * KD, e2g[bi], x2np);
      float od2 = __shfl_xor(bd, 32);
      int oi = __shfl_xor(bi, 32);
      if (od2 < bd || (od2 == bd && oi < bi)) { bd = od2; bi = oi; }
    }
  }

  // ---- epilogue: STE write + loss partial, static k-halves per gg
  const float4* eb4 = (const float4*)(etg + (size_t)bi * KD);
  float* op = out + (size_t)n * ZN + (size_t)g * ZG + tt;
  float ls = 0.f;
  if (gg == 0) {
#pragma unroll
    for (int p = 0; p < 5; ++p) {
      float4 v = eb4[p];
      int k = 4 * p;
      float e0 = __fsub_rn(v.x, x[k + 0]); ls = fmaf(e0, e0, ls); op[(size_t)(k + 0) * TP] = __fadd_rn(x[k + 0], e0);
      float e1 = __fsub_rn(v.y, x[k + 1]); ls = fmaf(e1, e1, ls); op[(size_t)(k + 1) * TP] = __fadd_rn(x[k + 1], e1);
      float e2v = __fsub_rn(v.z, x[k + 2]); ls = fmaf(e2v, e2v, ls); op[(size_t)(k + 2) * TP] = __fadd_rn(x[k + 2], e2v);
      float e3 = __fsub_rn(v.w, x[k + 3]); ls = fmaf(e3, e3, ls); op[(size_t)(k + 3) * TP] = __fadd_rn(x[k + 3], e3);
    }
  } else {
#pragma unroll
    for (int p = 5; p < 10; ++p) {
      float4 v = eb4[p];
      int k = 4 * p;
      float e0 = __fsub_rn(v.x, x[k + 0]); ls = fmaf(e0, e0, ls); op[(size_t)(k + 0) * TP] = __fadd_rn(x[k + 0], e0);
      float e1 = __fsub_rn(v.y, x[k + 1]); ls = fmaf(e1, e1, ls); op[(size_t)(k + 1) * TP] = __fadd_rn(x[k + 1], e1);
      float e2v = __fsub_rn(v.z, x[k + 2]); ls = fmaf(e2v, e2v, ls); op[(size_t)(k + 2) * TP] = __fadd_rn(x[k + 2], e2v);
      float e3 = __fsub_rn(v.w, x[k + 3]); ls = fmaf(e3, e3, ls); op[(size_t)(k + 3) * TP] = __fadd_rn(x[k + 3], e3);
    }
  }

  // ---- deterministic segmented block reduce (block straddles <=1 n boundary)
  const int n_lo = (bb * RPB) / TP;
  r0s[tid] = (n == n_lo) ? ls : 0.f;
  r1s[tid] = (n == n_lo) ? 0.f : ls;
  __syncthreads();
  for (int s = THREADS / 2; s > 0; s >>= 1) {
    if (tid < s) {
      r0s[tid] += r0s[tid + s];
      r1s[tid] += r1s[tid + s];
    }
    __syncthreads();
  }
  if (tid == 0) {
    partials[((size_t)g * NBLK + bb) * 2 + 0] = r0s[0];
    partials[((size_t)g * NBLK + bb) * 2 + 1] = r1s[0];
  }
}

// ---- final: fixed-order reduction of per-block partials -> vq_loss[n]
__global__ void loss_kernel(const float* __restrict__ partials,
                            float* __restrict__ vq) {
  int n = threadIdx.x;
  if (n >= NB) return;
  float acc = 0.f;
  for (int g = 0; g < NG; ++g) {
    float s = 0.f;
    int b0 = (n * TP) / RPB;
    int b1 = ((n + 1) * TP - 1) / RPB;
    for (int b = b0; b <= b1; ++b) {
      int n_lo = (b * RPB) / TP;
      s += partials[((size_t)g * NBLK + b) * 2 + ((n == n_lo) ? 0 : 1)];
    }
    acc += 0.25f * (s / 80000.0f);
  }
  vq[n] = acc / 6.0f;
}

extern "C" void kernel_launch(void* const* d_in, const int* in_sizes, int n_in,
                              void* d_out, int out_size, void* d_ws, size_t ws_size,
                              hipStream_t stream) {
  const float* z = (const float*)d_in[0];
  const float* emb = (const float*)d_in[1];
  float* out = (float*)d_out;

  float* et = (float*)d_ws;                          // 983,040 B
  float* e2 = et + (size_t)NG * CB * KD;             // 24,576 B
  float* partials = e2 + (size_t)NG * CB;            // 24,000 B
  unsigned short* epack = (unsigned short*)((char*)d_ws + 1031680);  // 1,179,648 B

  prep_kernel<<<dim3(CB / 256, NG), 256, 0, stream>>>(emb, et, e2, epack);
  vq_kernel<<<dim3(NBLK, NG), THREADS, 0, stream>>>(z, et, e2, epack, out, partials);
  loss_kernel<<<1, 64, 0, stream>>>(partials, out + (size_t)NB * 60 * 8000);
}

// Round 21
// 205.903 us; speedup vs baseline: 1.2993x; 1.1107x over previous
//
#include <hip/hip_runtime.h>
#include <math.h>

#define NG 6
#define KD 40
#define CB 1024
#define NB 32
#define TP 2000
#define RPB 128              // rows per block (4 waves x 32, gg-paired)
#define THREADS 256
#define NBLK 500             // 64000 / 128
#define ZN 480000
#define ZG 80000
#define BAND_D 6e-3f         // |approx_dist - np_dist| bound with >=2x margin
#define PK_G 98304           // shorts per group (32 tiles * 3072, hi+lo)
#define PK_T 3072            // shorts per tile
#define CHS 6144             // shorts per chunk (2 tiles)
#define NCH 16               // chunks

typedef __attribute__((ext_vector_type(8))) short bf16x8;
typedef __attribute__((ext_vector_type(16))) float f32x16;

__device__ __forceinline__ unsigned short bf16rne(float v) {
  unsigned u = __float_as_uint(v);
  return (unsigned short)((u + 0x7FFFu + ((u >> 16) & 1u)) >> 16);
}
__device__ __forceinline__ float bf16val(unsigned short h) {
  return __uint_as_float(((unsigned)h) << 16);
}
__device__ __forceinline__ void bf16split(float v, unsigned short& h, unsigned short& l) {
  h = bf16rne(v);
  l = bf16rne(v - bf16val(h));
}
__device__ __forceinline__ bf16x8 ldfrag16(const unsigned short* p) {
  union { uint4 q; bf16x8 v; } u;
  u.q = *(const uint4*)p;
  return u.v;
}
__device__ __forceinline__ void gload_lds16(const void* g, void* l) {
  __builtin_amdgcn_global_load_lds(
      (const __attribute__((address_space(1))) unsigned int*)g,
      (__attribute__((address_space(3))) unsigned int*)l, 16, 0, 0);
}

// ---- prep: et[g][c][k] fp32; np-exact ||e||^2; fragment-ordered bf16 hi/lo pack (r11)
__global__ void prep_kernel(const float* __restrict__ emb, float* __restrict__ et,
                            float* __restrict__ e2, unsigned short* __restrict__ epack) {
  int c = blockIdx.x * blockDim.x + threadIdx.x;
  int g = blockIdx.y;
  if (c >= CB) return;
  const float* eg = emb + (size_t)g * KD * CB;
  float ev[KD];
  float* o = et + ((size_t)g * CB + c) * KD;
  float s = 0.f;
#pragma unroll
  for (int k = 0; k < KD; ++k) {
    float v = eg[k * CB + c];
    ev[k] = v;
    o[k] = v;
    s = __fadd_rn(s, __fmul_rn(v, v));   // np-exact serial unfused
  }
  e2[g * CB + c] = s;

  float sv = 0.5f * s;                    // 3-way bf16 split of the seed
  unsigned short p0 = bf16rne(sv);
  float v1 = sv - bf16val(p0);
  unsigned short p1 = bf16rne(v1);
  unsigned short p2 = bf16rne(v1 - bf16val(p1));

  int tile = c >> 5, j32 = c & 31;
  unsigned short* tb = epack + (size_t)g * PK_G + (size_t)tile * PK_T;
#pragma unroll
  for (int s2 = 0; s2 < 3; ++s2)
#pragma unroll
    for (int gg = 0; gg < 2; ++gg) {
      union { uint4 q; unsigned short sh[8]; } uh, ul;
#pragma unroll
      for (int j = 0; j < 8; ++j) {
        int k = s2 * 16 + gg * 8 + j;
        if (k < KD) {
          bf16split(ev[k], uh.sh[j], ul.sh[j]);
        } else {
          uh.sh[j] = (k == 40) ? p0 : (k == 41) ? p1 : (k == 42) ? p2 : (unsigned short)0;
          ul.sh[j] = 0;
        }
      }
      unsigned short* ph = tb + ((size_t)(s2 * 2 + gg) * 32 + j32) * 8;
      *(uint4*)ph = uh.q;
      *(uint4*)(ph + 1536) = ul.q;
    }
}

__device__ __forceinline__ float npd_calc(const float* __restrict__ x,
                                          const float* __restrict__ ef,
                                          float e2c, float x2np) {
  float dot = 0.f;
#pragma unroll
  for (int k = 0; k < KD; ++k) dot = __fadd_rn(dot, __fmul_rn(x[k], ef[k]));
  return __fadd_rn(__fsub_rn(x2np, __fadd_rn(dot, dot)), e2c);
}

__global__ __launch_bounds__(THREADS, 3) void vq_kernel(
    const float* __restrict__ z, const float* __restrict__ et,
    const float* __restrict__ e2, const unsigned short* __restrict__ epack,
    float* __restrict__ out, float* __restrict__ partials) {
  const int g = blockIdx.y;
  const int bb = blockIdx.x;
  const int tid = threadIdx.x;
  const int lane = tid & 63;
  const int gg = lane >> 5;
  const int j32 = lane & 31;
  const int wid = tid >> 6;
  const int rowloc = wid * 32 + j32;
  const int rid = bb * RPB + rowloc;
  const int n = rid / TP;
  const int tt = rid - n * TP;

  const float* etg = et + (size_t)g * CB * KD;
  const float* e2g = e2 + g * CB;
  const unsigned short* egrp = epack + (size_t)g * PK_G;

  __shared__ __align__(16) unsigned short sbuf[3][CHS];   // 3-deep pipeline
  __shared__ float r0s[THREADS], r1s[THREADS];

#define STAGE(B, CH) { \
    const unsigned short* gsrc = egrp + (size_t)(CH) * CHS + wid * 512 + lane * 8; \
    unsigned short* lb = &sbuf[B][wid * 512]; \
    gload_lds16(gsrc, lb); \
    gload_lds16(gsrc + 2048, lb + 2048); \
    gload_lds16(gsrc + 4096, lb + 4096); }
  STAGE(0, 0)
  STAGE(1, 1)

  // ---- row x in registers; x2np (numpy pairwise-8, verified r6)
  const float* zp = z + (size_t)n * ZN + (size_t)g * ZG + tt;
  float x[KD];
#pragma unroll
  for (int k = 0; k < KD; ++k) x[k] = zp[(size_t)k * TP];
  float x2np;
  {
    float r[8];
#pragma unroll
    for (int j = 0; j < 8; ++j) r[j] = __fmul_rn(x[j], x[j]);
#pragma unroll
    for (int i = 8; i < KD; i += 8)
#pragma unroll
      for (int j = 0; j < 8; ++j)
        r[j] = __fadd_rn(r[j], __fmul_rn(x[i + j], x[i + j]));
    x2np = __fadd_rn(__fadd_rn(__fadd_rn(r[0], r[1]), __fadd_rn(r[2], r[3])),
                     __fadd_rn(__fadd_rn(r[4], r[5]), __fadd_rn(r[6], r[7])));
  }

  // ---- B fragments from -x, static per-gg k-slices (verified r9-r16)
  bf16x8 xh[3], xl[3];
#define PACK8(DH, DL, B0) { \
    union { unsigned short s[8]; bf16x8 v; } uh, ul; \
    _Pragma("unroll") \
    for (int j = 0; j < 8; ++j) { \
      unsigned short h, l; bf16split(-x[(B0) + j], h, l); \
      uh.s[j] = h; ul.s[j] = l; } \
    DH = uh.v; DL = ul.v; }
  if (gg == 0) {
    PACK8(xh[0], xl[0], 0)
    PACK8(xh[1], xl[1], 16)
    PACK8(xh[2], xl[2], 32)
  } else {
    PACK8(xh[0], xl[0], 8)
    PACK8(xh[1], xl[1], 24)
    union { unsigned short s[8]; bf16x8 v; } uh;
#pragma unroll
    for (int j = 0; j < 8; ++j) uh.s[j] = (j < 3) ? (unsigned short)0x3F80 : (unsigned short)0;
    xh[2] = uh.v;
    union { unsigned short s[8]; bf16x8 v; } uz;
#pragma unroll
    for (int j = 0; j < 8; ++j) uz.s[j] = 0;
    xl[2] = uz.v;
  }
#undef PACK8

  f32x16 zacc;
#pragma unroll
  for (int i = 0; i < 16; ++i) zacc[i] = 0.f;

  // ---- branchless tracking (verified r14): d1 + group base + d2x
  float d1 = INFINITY, d2x = INFINITY;
  int grp1 = 0;

#define TRACKG(AV, TILE) { \
    int cb = (TILE) * 32 + 4 * gg; \
    float q0 = fminf(fminf(fminf(AV[0], AV[1]), AV[2]), AV[3]); \
    float q1 = fminf(fminf(fminf(AV[4], AV[5]), AV[6]), AV[7]); \
    float q2 = fminf(fminf(fminf(AV[8], AV[9]), AV[10]), AV[11]); \
    float q3 = fminf(fminf(fminf(AV[12], AV[13]), AV[14]), AV[15]); \
    d2x = fminf(d2x, fmaxf(d1, q0)); grp1 = (q0 < d1) ? (cb + 0) : grp1; d1 = fminf(d1, q0); \
    d2x = fminf(d2x, fmaxf(d1, q1)); grp1 = (q1 < d1) ? (cb + 8) : grp1; d1 = fminf(d1, q1); \
    d2x = fminf(d2x, fmaxf(d1, q2)); grp1 = (q2 < d1) ? (cb + 16) : grp1; d1 = fminf(d1, q2); \
    d2x = fminf(d2x, fmaxf(d1, q3)); grp1 = (q3 < d1) ? (cb + 24) : grp1; d1 = fminf(d1, q3); }

#define MFMA9(TB, AOUT) { \
    bf16x8 eh0 = ldfrag16(TB); \
    bf16x8 eh1 = ldfrag16((TB) + 512); \
    bf16x8 eh2 = ldfrag16((TB) + 1024); \
    bf16x8 el0 = ldfrag16((TB) + 1536); \
    bf16x8 el1 = ldfrag16((TB) + 2048); \
    bf16x8 el2 = ldfrag16((TB) + 2560); \
    AOUT = __builtin_amdgcn_mfma_f32_32x32x16_bf16(eh0, xh[0], zacc, 0, 0, 0); \
    AOUT = __builtin_amdgcn_mfma_f32_32x32x16_bf16(eh0, xl[0], AOUT, 0, 0, 0); \
    AOUT = __builtin_amdgcn_mfma_f32_32x32x16_bf16(el0, xh[0], AOUT, 0, 0, 0); \
    AOUT = __builtin_amdgcn_mfma_f32_32x32x16_bf16(eh1, xh[1], AOUT, 0, 0, 0); \
    AOUT = __builtin_amdgcn_mfma_f32_32x32x16_bf16(eh1, xl[1], AOUT, 0, 0, 0); \
    AOUT = __builtin_amdgcn_mfma_f32_32x32x16_bf16(el1, xh[1], AOUT, 0, 0, 0); \
    AOUT = __builtin_amdgcn_mfma_f32_32x32x16_bf16(eh2, xh[2], AOUT, 0, 0, 0); \
    AOUT = __builtin_amdgcn_mfma_f32_32x32x16_bf16(eh2, xl[2], AOUT, 0, 0, 0); \
    AOUT = __builtin_amdgcn_mfma_f32_32x32x16_bf16(el2, xh[2], AOUT, 0, 0, 0); }

  // ---- T3/T4 pipeline: 3 buffers, ONE barrier per chunk, counted vmcnt.
  // Invariant at iter ch entry: chunks ch (oldest 3 DMAs) and ch+1 in flight.
  // vmcnt(3) -> own chunk-ch DMAs done; barrier -> ALL waves' done AND all
  // finished compute(ch-1); then STAGE(ch+2) may overwrite buf[(ch-1)%3].
  int cur = 0, stg = 2;
#pragma unroll 1
  for (int ch = 0; ch < NCH; ++ch) {
    if (ch < NCH - 1) {
      asm volatile("s_waitcnt vmcnt(3)" ::: "memory");
    } else {
      asm volatile("s_waitcnt vmcnt(0)" ::: "memory");
    }
    __builtin_amdgcn_s_barrier();
    if (ch + 2 < NCH) STAGE(stg, ch + 2)
    {
      f32x16 a0, a1;
      MFMA9(&sbuf[cur][lane * 8], a0)
      MFMA9(&sbuf[cur][PK_T + lane * 8], a1)
      TRACKG(a0, ch * 2)
      TRACKG(a1, ch * 2 + 1)
    }
    cur = (cur == 2) ? 0 : cur + 1;
    stg = (stg == 2) ? 0 : stg + 1;
  }

  // ---- end phase: np-exact rescore of the winning GROUP's 4 codes (r14-verified)
  float bd = INFINITY;
  int bi = CB;
#pragma unroll
  for (int j = 0; j < 4; ++j) {
    int c = grp1 + j;
    float d = npd_calc(x, etg + (size_t)c * KD, e2g[c], x2np);
    if (d < bd) { bd = d; bi = c; }
  }
  float dd2x = fmaf(2.f, d2x, x2np);

  // cross-half merge ((d,c) order; both bd are np-exact)
  {
    float od = __shfl_xor(bd, 32);
    int oi = __shfl_xor(bi, 32);
    float odd2x = __shfl_xor(dd2x, 32);
    if (od < bd || (od == bd && oi < bi)) { bd = od; bi = oi; }
    dd2x = fminf(dd2x, odd2x);
  }
  bool flag = dd2x < bd + BAND_D;  // another group might np-beat the winner

  // ---- rare wave-level fallback: exact top-3 rescan from GLOBAL epack (r13/r14)
  if (__any(flag)) {
    float rd1 = INFINITY, rd2 = INFINITY, rd3 = INFINITY;
    int ri1 = 0, ri2 = 0, ri3 = 0;
#define INS3(V, C) { \
      bool u1 = (V) < rd1, u2 = (V) < rd2, u3 = (V) < rd3; \
      rd3 = u2 ? rd2 : (u3 ? (V) : rd3); ri3 = u2 ? ri2 : (u3 ? (C) : ri3); \
      rd2 = u1 ? rd1 : (u2 ? (V) : rd2); ri2 = u1 ? ri1 : (u2 ? (C) : ri2); \
      rd1 = u1 ? (V) : rd1;              ri1 = u1 ? (C) : ri1; }
#pragma unroll 1
    for (int tile = 0; tile < 32; ++tile) {
      const unsigned short* tb = egrp + (size_t)tile * PK_T + lane * 8;
      f32x16 a;
      MFMA9(tb, a)
      {
        float gm0 = fminf(fminf(a[0], a[1]), fminf(a[2], a[3]));
        float gm1 = fminf(fminf(a[4], a[5]), fminf(a[6], a[7]));
        float gm2 = fminf(fminf(a[8], a[9]), fminf(a[10], a[11]));
        float gm3 = fminf(fminf(a[12], a[13]), fminf(a[14], a[15]));
        float tmin = fminf(fminf(gm0, gm1), fminf(gm2, gm3));
        if (tmin < rd3) {
          int cb = tile * 32 + 4 * gg;
          if (gm0 < rd3) { INS3(a[0], cb + 0) INS3(a[1], cb + 1) INS3(a[2], cb + 2) INS3(a[3], cb + 3) }
          if (gm1 < rd3) { INS3(a[4], cb + 8) INS3(a[5], cb + 9) INS3(a[6], cb + 10) INS3(a[7], cb + 11) }
          if (gm2 < rd3) { INS3(a[8], cb + 16) INS3(a[9], cb + 17) INS3(a[10], cb + 18) INS3(a[11], cb + 19) }
          if (gm3 < rd3) { INS3(a[12], cb + 24) INS3(a[13], cb + 25) INS3(a[14], cb + 26) INS3(a[15], cb + 27) }
        }
      }
    }
    float dd1 = fmaf(2.f, rd1, x2np);
    float dd2 = fmaf(2.f, rd2, x2np);
    float dd3 = fmaf(2.f, rd3, x2np);
    bd = dd1; bi = ri1;
    bool exact = false;
    {
      bool need2 = dd2 < dd1 + BAND_D;
      bool need3 = dd3 < dd1 + BAND_D;
      if (need2 || need3) {
        int cA = ri1;
        int cB = need2 ? ri2 : 0x7fffffff;
        int cC = need3 ? ri3 : 0x7fffffff;
        int t;
        if (cA > cB) { t = cA; cA = cB; cB = t; }
        if (cB > cC) { t = cB; cB = cC; cC = t; }
        if (cA > cB) { t = cA; cA = cB; cB = t; }
        bd = INFINITY; bi = CB;
        if (cA < CB) { float d = npd_calc(x, etg + (size_t)cA * KD, e2g[cA], x2np); if (d < bd) { bd = d; bi = cA; } }
        if (cB < CB) { float d = npd_calc(x, etg + (size_t)cB * KD, e2g[cB], x2np); if (d < bd) { bd = d; bi = cB; } }
        if (cC < CB) { float d = npd_calc(x, etg + (size_t)cC * KD, e2g[cC], x2np); if (d < bd) { bd = d; bi = cC; } }
        exact = true;
      }
    }
    {
      float od = __shfl_xor(bd, 32);
      bool race = fabsf(bd - od) < BAND_D;
      if (race && !exact) bd = npd_calc(x, etg + (size_t)bi * KD, e2g[bi], x2np);
      float od2 = __shfl_xor(bd, 32);
      int oi = __shfl_xor(bi, 32);
      if (od2 < bd || (od2 == bd && oi < bi)) { bd = od2; bi = oi; }
    }
  }

  // ---- epilogue: STE write + loss partial, static k-halves per gg
  const float4* eb4 = (const float4*)(etg + (size_t)bi * KD);
  float* op = out + (size_t)n * ZN + (size_t)g * ZG + tt;
  float ls = 0.f;
  if (gg == 0) {
#pragma unroll
    for (int p = 0; p < 5; ++p) {
      float4 v = eb4[p];
      int k = 4 * p;
      float e0 = __fsub_rn(v.x, x[k + 0]); ls = fmaf(e0, e0, ls); op[(size_t)(k + 0) * TP] = __fadd_rn(x[k + 0], e0);
      float e1 = __fsub_rn(v.y, x[k + 1]); ls = fmaf(e1, e1, ls); op[(size_t)(k + 1) * TP] = __fadd_rn(x[k + 1], e1);
      float e2v = __fsub_rn(v.z, x[k + 2]); ls = fmaf(e2v, e2v, ls); op[(size_t)(k + 2) * TP] = __fadd_rn(x[k + 2], e2v);
      float e3 = __fsub_rn(v.w, x[k + 3]); ls = fmaf(e3, e3, ls); op[(size_t)(k + 3) * TP] = __fadd_rn(x[k + 3], e3);
    }
  } else {
#pragma unroll
    for (int p = 5; p < 10; ++p) {
      float4 v = eb4[p];
      int k = 4 * p;
      float e0 = __fsub_rn(v.x, x[k + 0]); ls = fmaf(e0, e0, ls); op[(size_t)(k + 0) * TP] = __fadd_rn(x[k + 0], e0);
      float e1 = __fsub_rn(v.y, x[k + 1]); ls = fmaf(e1, e1, ls); op[(size_t)(k + 1) * TP] = __fadd_rn(x[k + 1], e1);
      float e2v = __fsub_rn(v.z, x[k + 2]); ls = fmaf(e2v, e2v, ls); op[(size_t)(k + 2) * TP] = __fadd_rn(x[k + 2], e2v);
      float e3 = __fsub_rn(v.w, x[k + 3]); ls = fmaf(e3, e3, ls); op[(size_t)(k + 3) * TP] = __fadd_rn(x[k + 3], e3);
    }
  }

  // ---- deterministic segmented block reduce (block straddles <=1 n boundary)
  const int n_lo = (bb * RPB) / TP;
  r0s[tid] = (n == n_lo) ? ls : 0.f;
  r1s[tid] = (n == n_lo) ? 0.f : ls;
  __syncthreads();
  for (int s = THREADS / 2; s > 0; s >>= 1) {
    if (tid < s) {
      r0s[tid] += r0s[tid + s];
      r1s[tid] += r1s[tid + s];
    }
    __syncthreads();
  }
  if (tid == 0) {
    partials[((size_t)g * NBLK + bb) * 2 + 0] = r0s[0];
    partials[((size_t)g * NBLK + bb) * 2 + 1] = r1s[0];
  }
}

// ---- final: fixed-order reduction of per-block partials -> vq_loss[n]
__global__ void loss_kernel(const float* __restrict__ partials,
                            float* __restrict__ vq) {
  int n = threadIdx.x;
  if (n >= NB) return;
  float acc = 0.f;
  for (int g = 0; g < NG; ++g) {
    float s = 0.f;
    int b0 = (n * TP) / RPB;
    int b1 = ((n + 1) * TP - 1) / RPB;
    for (int b = b0; b <= b1; ++b) {
      int n_lo = (b * RPB) / TP;
      s += partials[((size_t)g * NBLK + b) * 2 + ((n == n_lo) ? 0 : 1)];
    }
    acc += 0.25f * (s / 80000.0f);
  }
  vq[n] = acc / 6.0f;
}

extern "C" void kernel_launch(void* const* d_in, const int* in_sizes, int n_in,
                              void* d_out, int out_size, void* d_ws, size_t ws_size,
                              hipStream_t stream) {
  const float* z = (const float*)d_in[0];
  const float* emb = (const float*)d_in[1];
  float* out = (float*)d_out;

  float* et = (float*)d_ws;                          // 983,040 B
  float* e2 = et + (size_t)NG * CB * KD;             // 24,576 B
  float* partials = e2 + (size_t)NG * CB;            // 24,000 B
  unsigned short* epack = (unsigned short*)((char*)d_ws + 1031680);  // 1,179,648 B

  prep_kernel<<<dim3(CB / 256, NG), 256, 0, stream>>>(emb, et, e2, epack);
  vq_kernel<<<dim3(NBLK, NG), THREADS, 0, stream>>>(z, et, e2, epack, out, partials);
  loss_kernel<<<1, 64, 0, stream>>>(partials, out + (size_t)NB * 60 * 8000);
}